// Round 13
// baseline (321.705 us; speedup 1.0000x reference)
//
#include <hip/hip_runtime.h>
#include <hip/hip_bf16.h>

#define BB 4
#define CC 256
#define HW 4096
#define DD 128

typedef __attribute__((ext_vector_type(8))) short bf16x8;
typedef __attribute__((ext_vector_type(4))) short bf16x4;
typedef __attribute__((ext_vector_type(4))) float f32x4;
typedef __attribute__((ext_vector_type(16))) float f32x16;
typedef __attribute__((ext_vector_type(4))) unsigned uint4v;

static __device__ __forceinline__ void ld4(float* dst, const float* src) {
  float4 t = *(const float4*)src;
  dst[0] = t.x; dst[1] = t.y; dst[2] = t.z; dst[3] = t.w;
}

// float -> bf16 (RNE) raw bits
static __device__ __forceinline__ short f2b(float f) {
  unsigned u = __float_as_uint(f);
  u += 0x7fffu + ((u >> 16) & 1u);
  return (short)(u >> 16);
}
static __device__ __forceinline__ unsigned pk2(float lo, float hi) {
  return (unsigned)(unsigned short)f2b(lo) | ((unsigned)(unsigned short)f2b(hi) << 16);
}

// async global->LDS DMA, 16B per lane; LDS dest must be linear in lane order
static __device__ __forceinline__ void gl16(const short* g, short* l) {
  __builtin_amdgcn_global_load_lds(
      (const __attribute__((address_space(1))) unsigned*)g,
      (__attribute__((address_space(3))) unsigned*)l, 16, 0, 0);
}

// ---------------- K1: q/k/v 1x1 conv as LDS-staged bf16 MFMA.
// Per (pxtile, which, b): GEMM W(128x256) @ X(256x64px).
// Outputs: q,k -> (B,HW,128) bf16 (pre-transposed for attention);
//          v   -> (B,128,HW) bf16.
__global__ __launch_bounds__(256) void k_qkv_mfma(
    const float* __restrict__ src, const float* __restrict__ tgt,
    const float* __restrict__ Wq, const float* __restrict__ bq,
    const float* __restrict__ Wk, const float* __restrict__ bk,
    const float* __restrict__ Wv, const float* __restrict__ bv,
    short* __restrict__ qb, short* __restrict__ kb, short* __restrict__ vb)
{
  __shared__ __align__(16) short Wt[128 * 40];  // [ch][c], stride 40 (2-way free)
  __shared__ __align__(16) short Xt[64 * 40];   // [px][c]
  __shared__ __align__(16) short T[9216];       // epilogue tile
  const int tid = threadIdx.x;
  const int wv = tid >> 6;
  const int lane = tid & 63;
  const int t = lane & 15, q = lane >> 4;
  const int px0 = blockIdx.x * 64;
  const int which = blockIdx.y;
  const int b = blockIdx.z;
  const float* X    = (which == 0) ? src : tgt;
  const float* Wm   = (which == 0) ? Wq : (which == 1) ? Wk : Wv;
  const float* bias = (which == 0) ? bq : (which == 1) ? bk : bv;

  const f32x4 zf = {0.f, 0.f, 0.f, 0.f};
  f32x4 acc[2][4];
#pragma unroll
  for (int mt = 0; mt < 2; ++mt)
#pragma unroll
    for (int nt = 0; nt < 4; ++nt) acc[mt][nt] = zf;

  for (int kk = 0; kk < CC; kk += 32) {
    __syncthreads();
    // stage W tile: 128 ch x 32 c (f32 -> bf16)
#pragma unroll
    for (int u = 0; u < 4; ++u) {
      int e = tid + (u << 8);
      int row = e >> 3, cq = (e & 7) * 4;
      float4 w4 = *(const float4*)&Wm[row * CC + kk + cq];
      unsigned* dst = (unsigned*)(Wt + row * 40 + cq);
      dst[0] = pk2(w4.x, w4.y);
      dst[1] = pk2(w4.z, w4.w);
    }
    // stage X tile transposed: 32 c x 64 px -> Xt[px][c]
#pragma unroll
    for (int u = 0; u < 2; ++u) {
      int e = tid + (u << 8);
      int c = e >> 4, p4 = (e & 15) * 4;
      float4 xv = *(const float4*)&X[((size_t)b * CC + kk + c) * HW + px0 + p4];
      Xt[(p4 + 0) * 40 + c] = f2b(xv.x);
      Xt[(p4 + 1) * 40 + c] = f2b(xv.y);
      Xt[(p4 + 2) * 40 + c] = f2b(xv.z);
      Xt[(p4 + 3) * 40 + c] = f2b(xv.w);
    }
    __syncthreads();
    bf16x8 af[2], bfr[4];
#pragma unroll
    for (int mt = 0; mt < 2; ++mt)
      af[mt] = *(const bf16x8*)(Wt + (wv * 32 + mt * 16 + t) * 40 + q * 8);
#pragma unroll
    for (int nt = 0; nt < 4; ++nt)
      bfr[nt] = *(const bf16x8*)(Xt + (nt * 16 + t) * 40 + q * 8);
#pragma unroll
    for (int mt = 0; mt < 2; ++mt)
#pragma unroll
      for (int nt = 0; nt < 4; ++nt)
        acc[mt][nt] = __builtin_amdgcn_mfma_f32_16x16x32_bf16(
            af[mt], bfr[nt], acc[mt][nt], 0, 0, 0);
  }
  __syncthreads();
  // D mapping (verified idiom): ch = wv*32 + mt*16 + q*4 + r, px = nt*16 + t
  if (which < 2) {
    // T[px][ch], stride 136 -> coalesced (B,HW,128) store
#pragma unroll
    for (int mt = 0; mt < 2; ++mt) {
      int chb = wv * 32 + mt * 16 + q * 4;
#pragma unroll
      for (int r = 0; r < 4; ++r) {
        float bv_ = bias[chb + r];
#pragma unroll
        for (int nt = 0; nt < 4; ++nt)
          T[(nt * 16 + t) * 136 + chb + r] = f2b(acc[mt][nt][r] + bv_);
      }
    }
    __syncthreads();
    short* out = (which == 0) ? qb : kb;
    int p = tid >> 2, cq = (tid & 3) * 32;
    short* gdst = out + ((size_t)b * HW + px0 + p) * DD + cq;
#pragma unroll
    for (int e2 = 0; e2 < 4; ++e2)
      *(uint4*)(gdst + e2 * 8) = *(const uint4*)(T + p * 136 + cq + e2 * 8);
  } else {
    // T[ch][px], stride 72 -> coalesced (B,128,HW) store
#pragma unroll
    for (int mt = 0; mt < 2; ++mt) {
      int chb = wv * 32 + mt * 16 + q * 4;
#pragma unroll
      for (int r = 0; r < 4; ++r) {
        float bv_ = bias[chb + r];
#pragma unroll
        for (int nt = 0; nt < 4; ++nt)
          T[(chb + r) * 72 + nt * 16 + t] = f2b(acc[mt][nt][r] + bv_);
      }
    }
    __syncthreads();
    int ch = tid >> 1, pq = (tid & 1) * 32;
    short* gdst = vb + ((size_t)b * DD + ch) * HW + px0 + pq;
#pragma unroll
    for (int e2 = 0; e2 < 4; ++e2)
      *(uint4*)(gdst + e2 * 8) = *(const uint4*)(T + ch * 72 + pq + e2 * 8);
  }
}

// ---------------- K2: pass1 MFMA partial sums: rl[j] += sum_{i in range} exp(s[i,j])
// i-range split x4 across blockIdx.y for occupancy; rl pre-zeroed.
__global__ __launch_bounds__(256) void k_lsum2(
    const short* __restrict__ qb, const short* __restrict__ kb,
    float* __restrict__ rl)
{
  __shared__ float lred[4][64];
  const int tid = threadIdx.x;
  const int w = tid >> 6;
  const int lane = tid & 63;
  const int t = lane & 15, q = lane >> 4;
  const int j0 = blockIdx.x * 64;
  const int ibeg = blockIdx.y * 1024;
  const int b = blockIdx.z;
  const short* qbb = qb + (size_t)b * HW * DD;
  const short* kbb = kb + (size_t)b * HW * DD;

  bf16x8 Bq[4][4];
#pragma unroll
  for (int nt = 0; nt < 4; ++nt)
#pragma unroll
    for (int kk = 0; kk < 4; ++kk)
      Bq[nt][kk] = *(const bf16x8*)(qbb + (size_t)(j0 + nt * 16 + t) * DD + kk * 32 + q * 8);

  float racc[4] = {0.f, 0.f, 0.f, 0.f};
  const f32x4 zf = {0.f, 0.f, 0.f, 0.f};

  for (int i = ibeg + w * 16; i < ibeg + 1024; i += 64) {
    bf16x8 Ak[4];
#pragma unroll
    for (int kk = 0; kk < 4; ++kk)
      Ak[kk] = *(const bf16x8*)(kbb + (size_t)(i + t) * DD + kk * 32 + q * 8);
#pragma unroll
    for (int nt = 0; nt < 4; ++nt) {
      f32x4 d = zf;
#pragma unroll
      for (int kk = 0; kk < 4; ++kk)
        d = __builtin_amdgcn_mfma_f32_16x16x32_bf16(Ak[kk], Bq[nt][kk], d, 0, 0, 0);
      racc[nt] += __expf(d[0]) + __expf(d[1]) + __expf(d[2]) + __expf(d[3]);
    }
  }
#pragma unroll
  for (int nt = 0; nt < 4; ++nt) {
    float r = racc[nt];
    r += __shfl_xor(r, 16);
    r += __shfl_xor(r, 32);
    if (q == 0) lred[w][nt * 16 + t] = r;
  }
  __syncthreads();
  if (tid < 64) {
    float sum = lred[0][tid] + lred[1][tid] + lred[2][tid] + lred[3][tid];
    atomicAdd(&rl[(size_t)b * HW + j0 + tid], sum);
  }
}

// ---------------- K2b: vs[c][j] = bf16( vb[c][j] / l_j )   (B,128,HW)
__global__ __launch_bounds__(256) void k_vs(
    const short* __restrict__ vb, const float* __restrict__ rl,
    short* __restrict__ vs)
{
  int id4 = (blockIdx.x * 256 + threadIdx.x) * 4;
  int j = id4 & (HW - 1);
  int b = id4 >> 19;
  uint2 pv = *(const uint2*)(vb + id4);
  float f0 = __uint_as_float(pv.x << 16);
  float f1 = __uint_as_float(pv.x & 0xffff0000u);
  float f2 = __uint_as_float(pv.y << 16);
  float f3 = __uint_as_float(pv.y & 0xffff0000u);
  const float* rlb = rl + (size_t)b * HW + j;
  unsigned u0 = pk2(f0 / rlb[0], f1 / rlb[1]);
  unsigned u1 = pk2(f2 / rlb[2], f3 / rlb[3]);
  *(uint2*)(vs + id4) = make_uint2(u0, u1);
}

// ---------------- K3: pass2, 32x32x16 MFMA (R8-verified main loop).
// Epilogue modes: mode==0 -> f32 atomicAdd into ao (R11 behavior);
// mode==1 -> plain bf16 stores into per-js partial aop[js][B][HW][DD]
// (no atomics, no ao memset; k_proj fuses the 4-partial sum).
__global__ __launch_bounds__(256, 2) void k_attn2(
    const short* __restrict__ qb, const short* __restrict__ kb,
    const short* __restrict__ vs, float* __restrict__ ao,
    short* __restrict__ aop, int mode)
{
  __shared__ __align__(16) short Qs[2][64 * 128];   // [j][xor-swizzled c-granules]
  __shared__ __align__(16) short Vp[2][128 * 72];   // [c][kappa] permuted
  const int tid = threadIdx.x;
  const int w = tid >> 6;
  const int lane = tid & 63;
  const int l31 = lane & 31, h = lane >> 5;
  const int b = blockIdx.z;
  const int i0w = blockIdx.x * 128 + w * 32;
  const int jbeg = blockIdx.y * 1024, jend = jbeg + 1024;
  const short* qbb = qb + (size_t)b * HW * DD;
  const short* kbb = kb + (size_t)b * HW * DD;
  const short* vsb = vs + (size_t)b * DD * HW;

  bf16x8 Bk[8];
#pragma unroll
  for (int kk = 0; kk < 8; ++kk)
    Bk[kk] = *(const bf16x8*)(kbb + (size_t)(i0w + l31) * DD + kk * 16 + h * 8);

  f32x16 acc[4];
#pragma unroll
  for (int nt = 0; nt < 4; ++nt)
#pragma unroll
    for (int e = 0; e < 16; ++e) acc[nt][e] = 0.f;

  bf16x8 rq[4], rv[4];
#define LOADT(jt)                                                             \
  {                                                                           \
    _Pragma("unroll")                                                         \
    for (int r = 0; r < 4; ++r) {                                             \
      int e = tid + (r << 8);                                                 \
      rq[r] = *(const bf16x8*)(qbb + (size_t)((jt) + (e >> 4)) * DD +         \
                               (e & 15) * 8);                                 \
      rv[r] = *(const bf16x8*)(vsb + (size_t)(e >> 3) * HW + (jt) +           \
                               (e & 7) * 8);                                  \
    }                                                                         \
  }
#define WRITET(buf)                                                           \
  {                                                                           \
    _Pragma("unroll")                                                         \
    for (int r = 0; r < 4; ++r) {                                             \
      int e = tid + (r << 8);                                                 \
      int row = e >> 4;                                                       \
      int slot = (e & 15) ^ (row & 15);                                       \
      *(bf16x8*)(Qs[buf] + row * 128 + slot * 8) = rq[r];                     \
    }                                                                         \
    _Pragma("unroll")                                                         \
    for (int r = 0; r < 4; ++r) {                                             \
      int e = tid + (r << 8);                                                 \
      int c = e >> 3, u8 = e & 7;                                             \
      int kap = (u8 >> 2) * 32 + ((u8 >> 1) & 1) * 16 + (u8 & 1) * 4;         \
      bf16x4 lo = __builtin_shufflevector(rv[r], rv[r], 0, 1, 2, 3);          \
      bf16x4 hi = __builtin_shufflevector(rv[r], rv[r], 4, 5, 6, 7);          \
      *(bf16x4*)(Vp[buf] + c * 72 + kap) = lo;                                \
      *(bf16x4*)(Vp[buf] + c * 72 + kap + 8) = hi;                            \
    }                                                                         \
  }

  LOADT(jbeg);
  WRITET(0);
  LOADT(jbeg + 64);

  int cur = 0;
  for (int j = jbeg; j < jend; j += 64) {
    __syncthreads();
    if (j + 64 < jend) {
      WRITET(cur ^ 1);
      if (j + 128 < jend) LOADT(j + 128);
    }
    const short* Qb = Qs[cur];
    const short* Vb = Vp[cur];
    f32x16 sv[2];
#pragma unroll
    for (int ntj = 0; ntj < 2; ++ntj)
#pragma unroll
      for (int e = 0; e < 16; ++e) sv[ntj][e] = 0.f;
#pragma unroll
    for (int ntj = 0; ntj < 2; ++ntj)
#pragma unroll
      for (int kk = 0; kk < 8; ++kk) {
        int row = ntj * 32 + l31;
        int slot = (kk * 2 + h) ^ (row & 15);
        bf16x8 aq = *(const bf16x8*)(Qb + row * 128 + slot * 8);
        sv[ntj] = __builtin_amdgcn_mfma_f32_32x32x16_bf16(aq, Bk[kk], sv[ntj], 0, 0, 0);
      }
    bf16x8 ap[4];
#pragma unroll
    for (int s = 0; s < 4; ++s) {
      const int tI = s >> 1, base = (s & 1) * 8;
      unsigned w0 = pk2(__expf(sv[tI][base + 0]), __expf(sv[tI][base + 1]));
      unsigned w1 = pk2(__expf(sv[tI][base + 2]), __expf(sv[tI][base + 3]));
      unsigned w2 = pk2(__expf(sv[tI][base + 4]), __expf(sv[tI][base + 5]));
      unsigned w3 = pk2(__expf(sv[tI][base + 6]), __expf(sv[tI][base + 7]));
      uint4v pw = {w0, w1, w2, w3};
      ap[s] = __builtin_bit_cast(bf16x8, pw);
    }
#pragma unroll
    for (int ntc = 0; ntc < 4; ++ntc)
#pragma unroll
      for (int s = 0; s < 4; ++s) {
        bf16x8 bv = *(const bf16x8*)(Vb + (ntc * 32 + l31) * 72 + s * 16 + h * 8);
        acc[ntc] = __builtin_amdgcn_mfma_f32_32x32x16_bf16(ap[s], bv, acc[ntc], 0, 0, 0);
      }
    cur ^= 1;
  }
#undef LOADT
#undef WRITET
  if (mode) {
    // plain bf16 stores into this js-block's partial (written exactly once)
    short* pdst = aop + ((size_t)blockIdx.y * BB + b) * HW * DD;
#pragma unroll
    for (int ntc = 0; ntc < 4; ++ntc)
#pragma unroll
      for (int rg = 0; rg < 16; ++rg) {
        int i = i0w + (rg & 3) + 8 * (rg >> 2) + 4 * h;
        pdst[(size_t)i * DD + ntc * 32 + l31] = f2b(acc[ntc][rg]);
      }
  } else {
    float* aob = ao + (size_t)b * HW * DD;
#pragma unroll
    for (int ntc = 0; ntc < 4; ++ntc)
#pragma unroll
      for (int rg = 0; rg < 16; ++rg) {
        int i = i0w + (rg & 3) + 8 * (rg >> 2) + 4 * h;
        atomicAdd(&aob[(size_t)i * DD + ntc * 32 + l31], acc[ntc][rg]);
      }
  }
}

// ---------------- K4: y = tgt + gamma*(Wp@ao + bp) -> Xn interior, ch [0,256)
// mode==0: ao is f32 [B][HW][DD]. mode==1: sum 4 bf16 partials aop[js].
// Xn layout: (B,66,66,768) NHWC bf16, guard ring.
__global__ __launch_bounds__(256) void k_proj(
    const float* __restrict__ ao, const short* __restrict__ aop,
    const float* __restrict__ tgt,
    const float* __restrict__ Wp, const float* __restrict__ bp,
    const float* __restrict__ gamma, short* __restrict__ Xn, int mode)
{
  __shared__ float Wt[32][132];
  __shared__ float Xs[32][68];
  __shared__ float T[64][133];
  const int tid = threadIdx.x;
  const int tx = tid & 15, ty = tid >> 4;
  const int p0 = blockIdx.x * 64;
  const int ro = blockIdx.y * 128;
  const int b = blockIdx.z;
  const float g0 = gamma[0];

  float acc[8][4];
#pragma unroll
  for (int i = 0; i < 8; ++i)
#pragma unroll
    for (int j = 0; j < 4; ++j) acc[i][j] = 0.f;

  for (int kk = 0; kk < DD; kk += 32) {
    __syncthreads();
#pragma unroll
    for (int u = 0; u < 4; ++u) {
      int e = tid + 256 * u;
      int c4 = (e & 7) * 4, r = e >> 3;
      float w[4]; ld4(w, &Wp[(ro + r) * DD + kk + c4]);
      Wt[c4 + 0][r] = w[0]; Wt[c4 + 1][r] = w[1];
      Wt[c4 + 2][r] = w[2]; Wt[c4 + 3][r] = w[3];
    }
    // ao[i][c] (or 4 bf16 partials): load along c, transpose into Xs[c][p]
    if (mode) {
#pragma unroll
      for (int u = 0; u < 2; ++u) {
        int e = tid + 256 * u;
        int p = e >> 3, c4 = (e & 7) * 4;
        size_t base = ((size_t)b * HW + p0 + p) * DD + kk + c4;
        float v0 = 0.f, v1 = 0.f, v2 = 0.f, v3 = 0.f;
#pragma unroll
        for (int js = 0; js < 4; ++js) {
          uint2 pb = *(const uint2*)&aop[(size_t)js * BB * HW * DD + base];
          v0 += __uint_as_float(pb.x << 16);
          v1 += __uint_as_float(pb.x & 0xffff0000u);
          v2 += __uint_as_float(pb.y << 16);
          v3 += __uint_as_float(pb.y & 0xffff0000u);
        }
        Xs[c4 + 0][p] = v0; Xs[c4 + 1][p] = v1;
        Xs[c4 + 2][p] = v2; Xs[c4 + 3][p] = v3;
      }
    } else {
#pragma unroll
      for (int u = 0; u < 2; ++u) {
        int e = tid + 256 * u;
        int p = e >> 3, c4 = (e & 7) * 4;
        float4 v = *(const float4*)&ao[((size_t)b * HW + p0 + p) * DD + kk + c4];
        Xs[c4 + 0][p] = v.x; Xs[c4 + 1][p] = v.y;
        Xs[c4 + 2][p] = v.z; Xs[c4 + 3][p] = v.w;
      }
    }
    __syncthreads();
#pragma unroll 4
    for (int c = 0; c < 32; ++c) {
      float wa[8], xb[4];
      ld4(wa, &Wt[c][ty * 8]); ld4(wa + 4, &Wt[c][ty * 8 + 4]);
      ld4(xb, &Xs[c][tx * 4]);
#pragma unroll
      for (int rr = 0; rr < 8; ++rr)
#pragma unroll
        for (int pp = 0; pp < 4; ++pp) acc[rr][pp] += wa[rr] * xb[pp];
    }
  }
#pragma unroll
  for (int rr = 0; rr < 8; ++rr) {
    int r = ro + ty * 8 + rr;
    int idx = (b * CC + r) * HW + p0 + tx * 4;
    float4 t4 = *(const float4*)&tgt[idx];
    float bpv = bp[r];
    T[tx * 4 + 0][ty * 8 + rr] = t4.x + g0 * (acc[rr][0] + bpv);
    T[tx * 4 + 1][ty * 8 + rr] = t4.y + g0 * (acc[rr][1] + bpv);
    T[tx * 4 + 2][ty * 8 + rr] = t4.z + g0 * (acc[rr][2] + bpv);
    T[tx * 4 + 3][ty * 8 + rr] = t4.w + g0 * (acc[rr][3] + bpv);
  }
  __syncthreads();
  {
    int p = tid >> 2, cq = (tid & 3) * 32;
    int hh = p0 >> 6;
    unsigned* dst = (unsigned*)(Xn + ((((size_t)b * 66 + hh + 1) * 66) + 1 + p) * 768 + ro + cq);
#pragma unroll
    for (int e = 0; e < 16; ++e)
      dst[e] = pk2(T[p][cq + 2 * e], T[p][cq + 2 * e + 1]);
  }
}

// ---------------- K4b: upsample prev into Xn interior, channels [256,768)
__global__ __launch_bounds__(256) void k_pack(
    const float* __restrict__ prev, short* __restrict__ Xn)
{
  __shared__ float tile[64][65];
  const int tid = threadIdx.x;
  const int h = blockIdx.x;
  const int ci0 = blockIdx.y * 64;
  const int b = blockIdx.z;

  {
    int w = tid & 63, r = tid >> 6;
    for (int cs = r; cs < 64; cs += 4)
      tile[cs][w] = prev[((size_t)b * 512 + ci0 + cs) * 1024 + (h >> 1) * 32 + (w >> 1)];
  }
  __syncthreads();
  {
    int ci = tid & 63, wq = tid >> 6;
    for (int ws2 = wq; ws2 < 64; ws2 += 4)
      Xn[((((size_t)b * 66 + h + 1) * 66) + 1 + ws2) * 768 + 256 + ci0 + ci] = f2b(tile[ci][ws2]);
  }
}

// ---------------- K4c: weight repack Wc(256,768,3,3) f32 -> Wb(256,9,768) bf16
__global__ __launch_bounds__(256) void k_wb(
    const float* __restrict__ Wc, short* __restrict__ Wb)
{
  int i = blockIdx.x * 256 + threadIdx.x;
  int o = i / 6912;
  int rem = i - o * 6912;
  int khw = rem / 768;
  int ci = rem - khw * 768;
  Wb[i] = f2b(Wc[(size_t)o * 6912 + ci * 9 + khw]);
}

// ---------------- K5: 3x3 conv, 64x64 wave tiles + K-split x2, no atomics,
// now SOFTWARE-PIPELINED (T3/T4): 54 kw-granular stages, double-buffered
// W (2x16KB) and X (2x20KB incl. DMA pad), COUNTED vmcnt (never 0 in the
// main loop) so next-stage DMAs stay in flight across raw s_barriers:
//   per stage: [barrier A] [issue DMA(s+1): 4 W (+5 X at ci-cross)]
//              [s_waitcnt vmcnt(N_issued) -> stage-s data landed]
//              [sched_barrier] [barrier B] [16 ds_read + 32 MFMA]
// Barrier A separates stage s-1's readers from DMA(s+1) landing in the
// same buffer; barrier B publishes every wave's counted wait. X DMA is
// wave-uniform (5 instrs, clamp-free full-exec into padded LDS; pad reads
// stay inside the workspace) so per-wave vmcnt counts are uniform.
// Epilogue identical to R11/R12 (verified): ks=0 -> f32 into outf (=d_out),
// ks=1 -> bf16 into cb1; k_inorm fuses. Grid 32x4x4 = 2 blocks/CU.
__global__ __launch_bounds__(256, 2) void k_conv_mfma(
    const short* __restrict__ Xn,   // (B,66,66,768) bf16, guard ring zero
    const short* __restrict__ Wb,   // (256,9,768) bf16
    float* __restrict__ outf,       // (B,256,4096) f32: ks=0 partial (= d_out)
    short* __restrict__ cb1)        // (B,256,4096) bf16: ks=1 partial
{
  __shared__ __align__(16) short Wl[2][8192];   // [cout(128)][64ci] x2
  __shared__ __align__(16) short Xl[2][10240];  // rows 0..131 used; pad to 1280 slots
  const int tid = threadIdx.x;
  const int wv = tid >> 6;
  const int lane = tid & 63;
  const int t = lane & 15, q = lane >> 4;
  const int wm = wv >> 1, wn = wv & 1;
  const int h0 = blockIdx.x * 2;           // output rows h0, h0+1
  const int m0 = (blockIdx.y >> 1) * 128;  // cout half
  const int ks = blockIdx.y & 1;           // ci half
  const int b = blockIdx.z;

  const f32x4 zf = {0.f, 0.f, 0.f, 0.f};
  f32x4 acc[4][4];
#pragma unroll
  for (int mt = 0; mt < 4; ++mt)
#pragma unroll
    for (int nt = 0; nt < 4; ++nt) acc[mt][nt] = zf;

  // stage s in [0,54): kh = s/18, c6 = (s%18)/3, kw = s%3 ; X index xs = s/3
#define ISSUE_W(s_)                                                           \
  {                                                                           \
    int kh_ = (s_) / 18, r_ = (s_) % 18, c6_ = r_ / 3, kw_ = r_ % 3;          \
    const short* wsrc_ = Wb + (size_t)m0 * 6912 + (kh_ * 3 + kw_) * 768 +     \
                         ks * 384 + c6_ * 64;                                 \
    short* wdst_ = Wl[(s_) & 1];                                              \
    _Pragma("unroll")                                                         \
    for (int r = 0; r < 4; ++r) {                                             \
      int e = tid + (r << 8);                                                 \
      int g = e & 7, row = e >> 3;                                            \
      int gs = g ^ (row & 7);                                                 \
      gl16(wsrc_ + (size_t)row * 6912 + gs * 8, wdst_ + e * 8);               \
    }                                                                         \
  }
#define ISSUE_X(xs_)                                                          \
  {                                                                           \
    int kh_ = (xs_) / 6, c6_ = (xs_) % 6;                                     \
    const short* xsrc_ = Xn + ((size_t)b * 66 + h0 + kh_) * 66 * 768 +        \
                         ks * 384 + c6_ * 64;                                 \
    short* xdst_ = Xl[(xs_) & 1];                                             \
    _Pragma("unroll")                                                         \
    for (int r = 0; r < 5; ++r) {                                             \
      int e = tid + (r << 8);                                                 \
      int g = e & 7, prow = e >> 3;                                           \
      int xrow = (prow * 993) >> 16;   /* prow/66, exact for prow<1280 */     \
      int px = prow - xrow * 66;                                              \
      int gs = g ^ (prow & 7);                                                \
      gl16(xsrc_ + ((size_t)xrow * 66 + px) * 768 + gs * 8, xdst_ + e * 8);   \
    }                                                                         \
  }

  ISSUE_X(0);
  ISSUE_W(0);
  for (int s = 0; s < 54; ++s) {
    asm volatile("s_barrier" ::: "memory");           // A: prev readers done
    const int sn = s + 1;
    if (sn < 54) {
      ISSUE_W(sn);
      if (sn % 3 == 0) {
        ISSUE_X(sn / 3);
        asm volatile("s_waitcnt vmcnt(9)" ::: "memory");
      } else {
        asm volatile("s_waitcnt vmcnt(4)" ::: "memory");
      }
    } else {
      asm volatile("s_waitcnt vmcnt(0)" ::: "memory");
    }
    __builtin_amdgcn_sched_barrier(0);
    asm volatile("s_barrier" ::: "memory");           // B: stage-s data global
    {
      const int kw_ = s % 3;
      const short* Wlb = Wl[s & 1];
      const short* Xlb = Xl[(s / 3) & 1];
      bf16x8 af[4][2], bfr[4][2];
#pragma unroll
      for (int kk = 0; kk < 2; ++kk) {
#pragma unroll
        for (int mt = 0; mt < 4; ++mt) {
          int row = wm * 64 + mt * 16 + t;
          int g = (kk * 4 + q) ^ (row & 7);
          af[mt][kk] = *(const bf16x8*)(Wlb + row * 64 + g * 8);
        }
#pragma unroll
        for (int nt = 0; nt < 4; ++nt) {
          int prow = wn * 66 + nt * 16 + t + kw_;
          int g = (kk * 4 + q) ^ (prow & 7);
          bfr[nt][kk] = *(const bf16x8*)(Xlb + prow * 64 + g * 8);
        }
      }
#pragma unroll
      for (int kk = 0; kk < 2; ++kk)
#pragma unroll
        for (int mt = 0; mt < 4; ++mt)
#pragma unroll
          for (int nt = 0; nt < 4; ++nt)
            acc[mt][nt] = __builtin_amdgcn_mfma_f32_16x16x32_bf16(
                af[mt][kk], bfr[nt][kk], acc[mt][nt], 0, 0, 0);
    }
  }
#undef ISSUE_W
#undef ISSUE_X
  // epilogue: outch = m0 + wm*64 + mt*16 + q*4 + r ; out row = h0+wn ;
  // px-in-row = nt*16 + t. Plain stores to disjoint per-ks buffers.
  const int orow = h0 + wn;
  if (ks == 0) {
#pragma unroll
    for (int mt = 0; mt < 4; ++mt) {
      int om = m0 + wm * 64 + mt * 16 + q * 4;
#pragma unroll
      for (int r = 0; r < 4; ++r) {
        float* dst = outf + ((size_t)b * CC + om + r) * HW + orow * 64;
#pragma unroll
        for (int nt = 0; nt < 4; ++nt)
          dst[nt * 16 + t] = acc[mt][nt][r];
      }
    }
  } else {
#pragma unroll
    for (int mt = 0; mt < 4; ++mt) {
      int om = m0 + wm * 64 + mt * 16 + q * 4;
#pragma unroll
      for (int r = 0; r < 4; ++r) {
        short* dst = cb1 + ((size_t)b * CC + om + r) * HW + orow * 64;
#pragma unroll
        for (int nt = 0; nt < 4; ++nt)
          dst[nt * 16 + t] = f2b(acc[mt][nt][r]);
      }
    }
  }
}

// ---------------- K6: sum two conv partials (f32 + bf16), then
// InstanceNorm (biased var, eps=1e-5) + ReLU; writes d_out IN PLACE over
// the f32 partial. In/out alias -> no __restrict__; whole channel staged
// in LDS behind a barrier before any write; blocks own disjoint channels.
__global__ __launch_bounds__(256) void k_inorm(
    const float* p0, const short* __restrict__ p1, float* out)
{
  __shared__ float buf[4096];
  __shared__ float red[8];
  const int tid = threadIdx.x;
  const int ch = blockIdx.x;
  const float* s0 = p0 + (size_t)ch * HW;
  const short* s1 = p1 + (size_t)ch * HW;

  float s = 0.f, sq = 0.f;
#pragma unroll
  for (int u = 0; u < 4; ++u) {
    int idx = u * 1024 + tid * 4;
    float4 a = *(const float4*)&s0[idx];
    uint2 pb = *(const uint2*)&s1[idx];
    float v0 = a.x + __uint_as_float(pb.x << 16);
    float v1 = a.y + __uint_as_float(pb.x & 0xffff0000u);
    float v2 = a.z + __uint_as_float(pb.y << 16);
    float v3 = a.w + __uint_as_float(pb.y & 0xffff0000u);
    buf[idx + 0] = v0; buf[idx + 1] = v1;
    buf[idx + 2] = v2; buf[idx + 3] = v3;
    s += v0 + v1 + v2 + v3;
    sq += v0 * v0 + v1 * v1 + v2 * v2 + v3 * v3;
  }
#pragma unroll
  for (int m = 32; m >= 1; m >>= 1) {
    s  += __shfl_xor(s, m, 64);
    sq += __shfl_xor(sq, m, 64);
  }
  if ((tid & 63) == 0) { red[tid >> 6] = s; red[4 + (tid >> 6)] = sq; }
  __syncthreads();
  if (tid == 0) {
    float S = red[0] + red[1] + red[2] + red[3];
    float Q = red[4] + red[5] + red[6] + red[7];
    float mean = S * (1.f / HW);
    float var = Q * (1.f / HW) - mean * mean;
    red[0] = mean;
    red[1] = rsqrtf(var + 1e-5f);
  }
  __syncthreads();
  const float mean = red[0], rs = red[1];
#pragma unroll
  for (int u = 0; u < 4; ++u) {
    int idx = u * 1024 + tid * 4;
    float4 v = *(const float4*)&buf[idx];
    float4 o4 = make_float4(fmaxf((v.x - mean) * rs, 0.f),
                            fmaxf((v.y - mean) * rs, 0.f),
                            fmaxf((v.z - mean) * rs, 0.f),
                            fmaxf((v.w - mean) * rs, 0.f));
    *(float4*)&out[(size_t)ch * HW + idx] = o4;
  }
}

extern "C" void kernel_launch(void* const* d_in, const int* in_sizes, int n_in,
                              void* d_out, int out_size, void* d_ws, size_t ws_size,
                              hipStream_t stream) {
  const float* src  = (const float*)d_in[0];
  const float* tgt  = (const float*)d_in[1];
  const float* prev = (const float*)d_in[2];
  const float* Wq = (const float*)d_in[3];  const float* bq = (const float*)d_in[4];
  const float* Wk = (const float*)d_in[5];  const float* bk = (const float*)d_in[6];
  const float* Wv = (const float*)d_in[7];  const float* bv = (const float*)d_in[8];
  const float* Wp = (const float*)d_in[9];  const float* bp = (const float*)d_in[10];
  const float* gamma = (const float*)d_in[11];
  const float* Wc = (const float*)d_in[12];
  // bcw (d_in[13]) intentionally unused: InstanceNorm(affine=False) is
  // invariant to per-channel constant bias (and bc == 0 in this problem).

  float* ws = (float*)d_ws;
  // float-unit offsets; lifetimes:
  short* qb = (short*)ws;                 // [0, 1048576)        dead after k_attn2
  short* kb = (short*)(ws + 1048576);     // [1048576, 2097152)  dead after k_attn2
  short* vb = (short*)(ws + 2097152);     // [2097152, 3145728)  dead after k_vs
  float* rl = ws + 3145728;               // [3145728, 3162112)  dead after k_vs
  short* vs = (short*)(ws + 3162112);     // [3162112, 4210688)  dead after k_attn2
  short* Xn = (short*)ws;                 // [0, 6690816 floats) (B,66,66,768) bf16
  float* ao = ws + 6690816;               // [6690816, 8787968)  f32 (atomic mode only)
  short* Wb = (short*)(ws + 8787968);     // [8787968, 9672704)  written after k_proj
  float* outf = (float*)d_out;
  short* cb1 = (short*)(ws + 6690816);    // conv ks=1 bf16 partial (after proj)
  // Partial mode (needs ws >= 43,540,480 B): attn partials
  // aop[4][B][HW][DD] bf16 at [6690816, 10885120) — dead after k_proj,
  // so the Wb/cb1 overlaps are safe (both written after k_proj).
  short* aop = (short*)(ws + 6690816);
  const int mode = (ws_size >= 43540480ull) ? 1 : 0;

  k_qkv_mfma<<<dim3(64, 3, BB), 256, 0, stream>>>(src, tgt, Wq, bq, Wk, bk, Wv, bv, qb, kb, vb);
  hipMemsetAsync(rl, 0, (size_t)BB * HW * 4, stream);
  k_lsum2<<<dim3(64, 4, BB), 256, 0, stream>>>(qb, kb, rl);
  k_vs   <<<dim3(2048),      256, 0, stream>>>(vb, rl, vs);
  if (!mode) hipMemsetAsync(ao, 0, (size_t)2097152 * 4, stream);
  k_attn2<<<dim3(32, 4, BB), 256, 0, stream>>>(qb, kb, vs, ao, aop, mode);
  // Xn overlaps qb/kb/vb/rl/vs -> zero only after k_attn2 (also zeroes guard ring)
  hipMemsetAsync(Xn, 0, (size_t)BB * 66 * 66 * 768 * 2, stream);
  k_proj <<<dim3(64, 2, BB), 256, 0, stream>>>(ao, aop, tgt, Wp, bp, gamma, Xn, mode);
  k_pack <<<dim3(64, 8, BB), 256, 0, stream>>>(prev, Xn);
  k_wb   <<<dim3(6912),      256, 0, stream>>>(Wc, Wb);
  k_conv_mfma<<<dim3(32, 4, BB), 256, 0, stream>>>(Xn, Wb, outf, cb1);
  k_inorm<<<dim3(1024),      256, 0, stream>>>(outf, cb1, (float*)d_out);
}

// Round 14
// 314.512 us; speedup vs baseline: 1.0229x; 1.0229x over previous
//
#include <hip/hip_runtime.h>
#include <hip/hip_bf16.h>

#define BB 4
#define CC 256
#define HW 4096
#define DD 128

typedef __attribute__((ext_vector_type(8))) short bf16x8;
typedef __attribute__((ext_vector_type(4))) short bf16x4;
typedef __attribute__((ext_vector_type(4))) float f32x4;
typedef __attribute__((ext_vector_type(16))) float f32x16;
typedef __attribute__((ext_vector_type(4))) unsigned uint4v;

static __device__ __forceinline__ void ld4(float* dst, const float* src) {
  float4 t = *(const float4*)src;
  dst[0] = t.x; dst[1] = t.y; dst[2] = t.z; dst[3] = t.w;
}

// float -> bf16 (RNE) raw bits
static __device__ __forceinline__ short f2b(float f) {
  unsigned u = __float_as_uint(f);
  u += 0x7fffu + ((u >> 16) & 1u);
  return (short)(u >> 16);
}
static __device__ __forceinline__ unsigned pk2(float lo, float hi) {
  return (unsigned)(unsigned short)f2b(lo) | ((unsigned)(unsigned short)f2b(hi) << 16);
}

// async global->LDS DMA, 16B per lane; LDS dest must be linear in lane order
static __device__ __forceinline__ void gl16(const short* g, short* l) {
  __builtin_amdgcn_global_load_lds(
      (const __attribute__((address_space(1))) unsigned*)g,
      (__attribute__((address_space(3))) unsigned*)l, 16, 0, 0);
}

// ---------------- K1: q/k/v 1x1 conv as LDS-staged bf16 MFMA.
// Per (pxtile, which, b): GEMM W(128x256) @ X(256x64px).
// Outputs: q,k -> (B,HW,128) bf16 (pre-transposed for attention);
//          v   -> (B,128,HW) bf16.
__global__ __launch_bounds__(256) void k_qkv_mfma(
    const float* __restrict__ src, const float* __restrict__ tgt,
    const float* __restrict__ Wq, const float* __restrict__ bq,
    const float* __restrict__ Wk, const float* __restrict__ bk,
    const float* __restrict__ Wv, const float* __restrict__ bv,
    short* __restrict__ qb, short* __restrict__ kb, short* __restrict__ vb)
{
  __shared__ __align__(16) short Wt[128 * 40];  // [ch][c], stride 40 (2-way free)
  __shared__ __align__(16) short Xt[64 * 40];   // [px][c]
  __shared__ __align__(16) short T[9216];       // epilogue tile
  const int tid = threadIdx.x;
  const int wv = tid >> 6;
  const int lane = tid & 63;
  const int t = lane & 15, q = lane >> 4;
  const int px0 = blockIdx.x * 64;
  const int which = blockIdx.y;
  const int b = blockIdx.z;
  const float* X    = (which == 0) ? src : tgt;
  const float* Wm   = (which == 0) ? Wq : (which == 1) ? Wk : Wv;
  const float* bias = (which == 0) ? bq : (which == 1) ? bk : bv;

  const f32x4 zf = {0.f, 0.f, 0.f, 0.f};
  f32x4 acc[2][4];
#pragma unroll
  for (int mt = 0; mt < 2; ++mt)
#pragma unroll
    for (int nt = 0; nt < 4; ++nt) acc[mt][nt] = zf;

  for (int kk = 0; kk < CC; kk += 32) {
    __syncthreads();
    // stage W tile: 128 ch x 32 c (f32 -> bf16)
#pragma unroll
    for (int u = 0; u < 4; ++u) {
      int e = tid + (u << 8);
      int row = e >> 3, cq = (e & 7) * 4;
      float4 w4 = *(const float4*)&Wm[row * CC + kk + cq];
      unsigned* dst = (unsigned*)(Wt + row * 40 + cq);
      dst[0] = pk2(w4.x, w4.y);
      dst[1] = pk2(w4.z, w4.w);
    }
    // stage X tile transposed: 32 c x 64 px -> Xt[px][c]
#pragma unroll
    for (int u = 0; u < 2; ++u) {
      int e = tid + (u << 8);
      int c = e >> 4, p4 = (e & 15) * 4;
      float4 xv = *(const float4*)&X[((size_t)b * CC + kk + c) * HW + px0 + p4];
      Xt[(p4 + 0) * 40 + c] = f2b(xv.x);
      Xt[(p4 + 1) * 40 + c] = f2b(xv.y);
      Xt[(p4 + 2) * 40 + c] = f2b(xv.z);
      Xt[(p4 + 3) * 40 + c] = f2b(xv.w);
    }
    __syncthreads();
    bf16x8 af[2], bfr[4];
#pragma unroll
    for (int mt = 0; mt < 2; ++mt)
      af[mt] = *(const bf16x8*)(Wt + (wv * 32 + mt * 16 + t) * 40 + q * 8);
#pragma unroll
    for (int nt = 0; nt < 4; ++nt)
      bfr[nt] = *(const bf16x8*)(Xt + (nt * 16 + t) * 40 + q * 8);
#pragma unroll
    for (int mt = 0; mt < 2; ++mt)
#pragma unroll
      for (int nt = 0; nt < 4; ++nt)
        acc[mt][nt] = __builtin_amdgcn_mfma_f32_16x16x32_bf16(
            af[mt], bfr[nt], acc[mt][nt], 0, 0, 0);
  }
  __syncthreads();
  // D mapping (verified idiom): ch = wv*32 + mt*16 + q*4 + r, px = nt*16 + t
  if (which < 2) {
    // T[px][ch], stride 136 -> coalesced (B,HW,128) store
#pragma unroll
    for (int mt = 0; mt < 2; ++mt) {
      int chb = wv * 32 + mt * 16 + q * 4;
#pragma unroll
      for (int r = 0; r < 4; ++r) {
        float bv_ = bias[chb + r];
#pragma unroll
        for (int nt = 0; nt < 4; ++nt)
          T[(nt * 16 + t) * 136 + chb + r] = f2b(acc[mt][nt][r] + bv_);
      }
    }
    __syncthreads();
    short* out = (which == 0) ? qb : kb;
    int p = tid >> 2, cq = (tid & 3) * 32;
    short* gdst = out + ((size_t)b * HW + px0 + p) * DD + cq;
#pragma unroll
    for (int e2 = 0; e2 < 4; ++e2)
      *(uint4*)(gdst + e2 * 8) = *(const uint4*)(T + p * 136 + cq + e2 * 8);
  } else {
    // T[ch][px], stride 72 -> coalesced (B,128,HW) store
#pragma unroll
    for (int mt = 0; mt < 2; ++mt) {
      int chb = wv * 32 + mt * 16 + q * 4;
#pragma unroll
      for (int r = 0; r < 4; ++r) {
        float bv_ = bias[chb + r];
#pragma unroll
        for (int nt = 0; nt < 4; ++nt)
          T[(chb + r) * 72 + nt * 16 + t] = f2b(acc[mt][nt][r] + bv_);
      }
    }
    __syncthreads();
    int ch = tid >> 1, pq = (tid & 1) * 32;
    short* gdst = vb + ((size_t)b * DD + ch) * HW + px0 + pq;
#pragma unroll
    for (int e2 = 0; e2 < 4; ++e2)
      *(uint4*)(gdst + e2 * 8) = *(const uint4*)(T + ch * 72 + pq + e2 * 8);
  }
}

// ---------------- K2: pass1 MFMA partial sums: rl[j] += sum_{i in range} exp(s[i,j])
// i-range split x4 across blockIdx.y for occupancy; rl pre-zeroed.
__global__ __launch_bounds__(256) void k_lsum2(
    const short* __restrict__ qb, const short* __restrict__ kb,
    float* __restrict__ rl)
{
  __shared__ float lred[4][64];
  const int tid = threadIdx.x;
  const int w = tid >> 6;
  const int lane = tid & 63;
  const int t = lane & 15, q = lane >> 4;
  const int j0 = blockIdx.x * 64;
  const int ibeg = blockIdx.y * 1024;
  const int b = blockIdx.z;
  const short* qbb = qb + (size_t)b * HW * DD;
  const short* kbb = kb + (size_t)b * HW * DD;

  bf16x8 Bq[4][4];
#pragma unroll
  for (int nt = 0; nt < 4; ++nt)
#pragma unroll
    for (int kk = 0; kk < 4; ++kk)
      Bq[nt][kk] = *(const bf16x8*)(qbb + (size_t)(j0 + nt * 16 + t) * DD + kk * 32 + q * 8);

  float racc[4] = {0.f, 0.f, 0.f, 0.f};
  const f32x4 zf = {0.f, 0.f, 0.f, 0.f};

  for (int i = ibeg + w * 16; i < ibeg + 1024; i += 64) {
    bf16x8 Ak[4];
#pragma unroll
    for (int kk = 0; kk < 4; ++kk)
      Ak[kk] = *(const bf16x8*)(kbb + (size_t)(i + t) * DD + kk * 32 + q * 8);
#pragma unroll
    for (int nt = 0; nt < 4; ++nt) {
      f32x4 d = zf;
#pragma unroll
      for (int kk = 0; kk < 4; ++kk)
        d = __builtin_amdgcn_mfma_f32_16x16x32_bf16(Ak[kk], Bq[nt][kk], d, 0, 0, 0);
      racc[nt] += __expf(d[0]) + __expf(d[1]) + __expf(d[2]) + __expf(d[3]);
    }
  }
#pragma unroll
  for (int nt = 0; nt < 4; ++nt) {
    float r = racc[nt];
    r += __shfl_xor(r, 16);
    r += __shfl_xor(r, 32);
    if (q == 0) lred[w][nt * 16 + t] = r;
  }
  __syncthreads();
  if (tid < 64) {
    float sum = lred[0][tid] + lred[1][tid] + lred[2][tid] + lred[3][tid];
    atomicAdd(&rl[(size_t)b * HW + j0 + tid], sum);
  }
}

// ---------------- K2b: vs[c][j] = bf16( vb[c][j] / l_j )   (B,128,HW)
__global__ __launch_bounds__(256) void k_vs(
    const short* __restrict__ vb, const float* __restrict__ rl,
    short* __restrict__ vs)
{
  int id4 = (blockIdx.x * 256 + threadIdx.x) * 4;
  int j = id4 & (HW - 1);
  int b = id4 >> 19;
  uint2 pv = *(const uint2*)(vb + id4);
  float f0 = __uint_as_float(pv.x << 16);
  float f1 = __uint_as_float(pv.x & 0xffff0000u);
  float f2 = __uint_as_float(pv.y << 16);
  float f3 = __uint_as_float(pv.y & 0xffff0000u);
  const float* rlb = rl + (size_t)b * HW + j;
  unsigned u0 = pk2(f0 / rlb[0], f1 / rlb[1]);
  unsigned u1 = pk2(f2 / rlb[2], f3 / rlb[3]);
  *(uint2*)(vs + id4) = make_uint2(u0, u1);
}

// ---------------- K3: pass2, 32x32x16 MFMA (R8-verified main loop).
// Epilogue modes: mode==0 -> f32 atomicAdd into ao (R11 behavior);
// mode==1 -> plain bf16 stores into per-js partial aop[js][B][HW][DD]
// (no atomics, no ao memset; k_proj fuses the 4-partial sum).
__global__ __launch_bounds__(256, 2) void k_attn2(
    const short* __restrict__ qb, const short* __restrict__ kb,
    const short* __restrict__ vs, float* __restrict__ ao,
    short* __restrict__ aop, int mode)
{
  __shared__ __align__(16) short Qs[2][64 * 128];   // [j][xor-swizzled c-granules]
  __shared__ __align__(16) short Vp[2][128 * 72];   // [c][kappa] permuted
  const int tid = threadIdx.x;
  const int w = tid >> 6;
  const int lane = tid & 63;
  const int l31 = lane & 31, h = lane >> 5;
  const int b = blockIdx.z;
  const int i0w = blockIdx.x * 128 + w * 32;
  const int jbeg = blockIdx.y * 1024, jend = jbeg + 1024;
  const short* qbb = qb + (size_t)b * HW * DD;
  const short* kbb = kb + (size_t)b * HW * DD;
  const short* vsb = vs + (size_t)b * DD * HW;

  bf16x8 Bk[8];
#pragma unroll
  for (int kk = 0; kk < 8; ++kk)
    Bk[kk] = *(const bf16x8*)(kbb + (size_t)(i0w + l31) * DD + kk * 16 + h * 8);

  f32x16 acc[4];
#pragma unroll
  for (int nt = 0; nt < 4; ++nt)
#pragma unroll
    for (int e = 0; e < 16; ++e) acc[nt][e] = 0.f;

  bf16x8 rq[4], rv[4];
#define LOADT(jt)                                                             \
  {                                                                           \
    _Pragma("unroll")                                                         \
    for (int r = 0; r < 4; ++r) {                                             \
      int e = tid + (r << 8);                                                 \
      rq[r] = *(const bf16x8*)(qbb + (size_t)((jt) + (e >> 4)) * DD +         \
                               (e & 15) * 8);                                 \
      rv[r] = *(const bf16x8*)(vsb + (size_t)(e >> 3) * HW + (jt) +           \
                               (e & 7) * 8);                                  \
    }                                                                         \
  }
#define WRITET(buf)                                                           \
  {                                                                           \
    _Pragma("unroll")                                                         \
    for (int r = 0; r < 4; ++r) {                                             \
      int e = tid + (r << 8);                                                 \
      int row = e >> 4;                                                       \
      int slot = (e & 15) ^ (row & 15);                                       \
      *(bf16x8*)(Qs[buf] + row * 128 + slot * 8) = rq[r];                     \
    }                                                                         \
    _Pragma("unroll")                                                         \
    for (int r = 0; r < 4; ++r) {                                             \
      int e = tid + (r << 8);                                                 \
      int c = e >> 3, u8 = e & 7;                                             \
      int kap = (u8 >> 2) * 32 + ((u8 >> 1) & 1) * 16 + (u8 & 1) * 4;         \
      bf16x4 lo = __builtin_shufflevector(rv[r], rv[r], 0, 1, 2, 3);          \
      bf16x4 hi = __builtin_shufflevector(rv[r], rv[r], 4, 5, 6, 7);          \
      *(bf16x4*)(Vp[buf] + c * 72 + kap) = lo;                                \
      *(bf16x4*)(Vp[buf] + c * 72 + kap + 8) = hi;                            \
    }                                                                         \
  }

  LOADT(jbeg);
  WRITET(0);
  LOADT(jbeg + 64);

  int cur = 0;
  for (int j = jbeg; j < jend; j += 64) {
    __syncthreads();
    if (j + 64 < jend) {
      WRITET(cur ^ 1);
      if (j + 128 < jend) LOADT(j + 128);
    }
    const short* Qb = Qs[cur];
    const short* Vb = Vp[cur];
    f32x16 sv[2];
#pragma unroll
    for (int ntj = 0; ntj < 2; ++ntj)
#pragma unroll
      for (int e = 0; e < 16; ++e) sv[ntj][e] = 0.f;
#pragma unroll
    for (int ntj = 0; ntj < 2; ++ntj)
#pragma unroll
      for (int kk = 0; kk < 8; ++kk) {
        int row = ntj * 32 + l31;
        int slot = (kk * 2 + h) ^ (row & 15);
        bf16x8 aq = *(const bf16x8*)(Qb + row * 128 + slot * 8);
        sv[ntj] = __builtin_amdgcn_mfma_f32_32x32x16_bf16(aq, Bk[kk], sv[ntj], 0, 0, 0);
      }
    bf16x8 ap[4];
#pragma unroll
    for (int s = 0; s < 4; ++s) {
      const int tI = s >> 1, base = (s & 1) * 8;
      unsigned w0 = pk2(__expf(sv[tI][base + 0]), __expf(sv[tI][base + 1]));
      unsigned w1 = pk2(__expf(sv[tI][base + 2]), __expf(sv[tI][base + 3]));
      unsigned w2 = pk2(__expf(sv[tI][base + 4]), __expf(sv[tI][base + 5]));
      unsigned w3 = pk2(__expf(sv[tI][base + 6]), __expf(sv[tI][base + 7]));
      uint4v pw = {w0, w1, w2, w3};
      ap[s] = __builtin_bit_cast(bf16x8, pw);
    }
#pragma unroll
    for (int ntc = 0; ntc < 4; ++ntc)
#pragma unroll
      for (int s = 0; s < 4; ++s) {
        bf16x8 bv = *(const bf16x8*)(Vb + (ntc * 32 + l31) * 72 + s * 16 + h * 8);
        acc[ntc] = __builtin_amdgcn_mfma_f32_32x32x16_bf16(ap[s], bv, acc[ntc], 0, 0, 0);
      }
    cur ^= 1;
  }
#undef LOADT
#undef WRITET
  if (mode) {
    // plain bf16 stores into this js-block's partial (written exactly once)
    short* pdst = aop + ((size_t)blockIdx.y * BB + b) * HW * DD;
#pragma unroll
    for (int ntc = 0; ntc < 4; ++ntc)
#pragma unroll
      for (int rg = 0; rg < 16; ++rg) {
        int i = i0w + (rg & 3) + 8 * (rg >> 2) + 4 * h;
        pdst[(size_t)i * DD + ntc * 32 + l31] = f2b(acc[ntc][rg]);
      }
  } else {
    float* aob = ao + (size_t)b * HW * DD;
#pragma unroll
    for (int ntc = 0; ntc < 4; ++ntc)
#pragma unroll
      for (int rg = 0; rg < 16; ++rg) {
        int i = i0w + (rg & 3) + 8 * (rg >> 2) + 4 * h;
        atomicAdd(&aob[(size_t)i * DD + ntc * 32 + l31], acc[ntc][rg]);
      }
  }
}

// ---------------- K4: y = tgt + gamma*(Wp@ao + bp) -> Xn interior, ch [0,256)
// mode==0: ao is f32 [B][HW][DD]. mode==1: sum 4 bf16 partials aop[js].
// Xn layout: (B,66,66,768) NHWC bf16, guard ring.
__global__ __launch_bounds__(256) void k_proj(
    const float* __restrict__ ao, const short* __restrict__ aop,
    const float* __restrict__ tgt,
    const float* __restrict__ Wp, const float* __restrict__ bp,
    const float* __restrict__ gamma, short* __restrict__ Xn, int mode)
{
  __shared__ float Wt[32][132];
  __shared__ float Xs[32][68];
  __shared__ float T[64][133];
  const int tid = threadIdx.x;
  const int tx = tid & 15, ty = tid >> 4;
  const int p0 = blockIdx.x * 64;
  const int ro = blockIdx.y * 128;
  const int b = blockIdx.z;
  const float g0 = gamma[0];

  float acc[8][4];
#pragma unroll
  for (int i = 0; i < 8; ++i)
#pragma unroll
    for (int j = 0; j < 4; ++j) acc[i][j] = 0.f;

  for (int kk = 0; kk < DD; kk += 32) {
    __syncthreads();
#pragma unroll
    for (int u = 0; u < 4; ++u) {
      int e = tid + 256 * u;
      int c4 = (e & 7) * 4, r = e >> 3;
      float w[4]; ld4(w, &Wp[(ro + r) * DD + kk + c4]);
      Wt[c4 + 0][r] = w[0]; Wt[c4 + 1][r] = w[1];
      Wt[c4 + 2][r] = w[2]; Wt[c4 + 3][r] = w[3];
    }
    // ao[i][c] (or 4 bf16 partials): load along c, transpose into Xs[c][p]
    if (mode) {
#pragma unroll
      for (int u = 0; u < 2; ++u) {
        int e = tid + 256 * u;
        int p = e >> 3, c4 = (e & 7) * 4;
        size_t base = ((size_t)b * HW + p0 + p) * DD + kk + c4;
        float v0 = 0.f, v1 = 0.f, v2 = 0.f, v3 = 0.f;
#pragma unroll
        for (int js = 0; js < 4; ++js) {
          uint2 pb = *(const uint2*)&aop[(size_t)js * BB * HW * DD + base];
          v0 += __uint_as_float(pb.x << 16);
          v1 += __uint_as_float(pb.x & 0xffff0000u);
          v2 += __uint_as_float(pb.y << 16);
          v3 += __uint_as_float(pb.y & 0xffff0000u);
        }
        Xs[c4 + 0][p] = v0; Xs[c4 + 1][p] = v1;
        Xs[c4 + 2][p] = v2; Xs[c4 + 3][p] = v3;
      }
    } else {
#pragma unroll
      for (int u = 0; u < 2; ++u) {
        int e = tid + 256 * u;
        int p = e >> 3, c4 = (e & 7) * 4;
        float4 v = *(const float4*)&ao[((size_t)b * HW + p0 + p) * DD + kk + c4];
        Xs[c4 + 0][p] = v.x; Xs[c4 + 1][p] = v.y;
        Xs[c4 + 2][p] = v.z; Xs[c4 + 3][p] = v.w;
      }
    }
    __syncthreads();
#pragma unroll 4
    for (int c = 0; c < 32; ++c) {
      float wa[8], xb[4];
      ld4(wa, &Wt[c][ty * 8]); ld4(wa + 4, &Wt[c][ty * 8 + 4]);
      ld4(xb, &Xs[c][tx * 4]);
#pragma unroll
      for (int rr = 0; rr < 8; ++rr)
#pragma unroll
        for (int pp = 0; pp < 4; ++pp) acc[rr][pp] += wa[rr] * xb[pp];
    }
  }
#pragma unroll
  for (int rr = 0; rr < 8; ++rr) {
    int r = ro + ty * 8 + rr;
    int idx = (b * CC + r) * HW + p0 + tx * 4;
    float4 t4 = *(const float4*)&tgt[idx];
    float bpv = bp[r];
    T[tx * 4 + 0][ty * 8 + rr] = t4.x + g0 * (acc[rr][0] + bpv);
    T[tx * 4 + 1][ty * 8 + rr] = t4.y + g0 * (acc[rr][1] + bpv);
    T[tx * 4 + 2][ty * 8 + rr] = t4.z + g0 * (acc[rr][2] + bpv);
    T[tx * 4 + 3][ty * 8 + rr] = t4.w + g0 * (acc[rr][3] + bpv);
  }
  __syncthreads();
  {
    int p = tid >> 2, cq = (tid & 3) * 32;
    int hh = p0 >> 6;
    unsigned* dst = (unsigned*)(Xn + ((((size_t)b * 66 + hh + 1) * 66) + 1 + p) * 768 + ro + cq);
#pragma unroll
    for (int e = 0; e < 16; ++e)
      dst[e] = pk2(T[p][cq + 2 * e], T[p][cq + 2 * e + 1]);
  }
}

// ---------------- K4b: upsample prev into Xn interior, channels [256,768)
__global__ __launch_bounds__(256) void k_pack(
    const float* __restrict__ prev, short* __restrict__ Xn)
{
  __shared__ float tile[64][65];
  const int tid = threadIdx.x;
  const int h = blockIdx.x;
  const int ci0 = blockIdx.y * 64;
  const int b = blockIdx.z;

  {
    int w = tid & 63, r = tid >> 6;
    for (int cs = r; cs < 64; cs += 4)
      tile[cs][w] = prev[((size_t)b * 512 + ci0 + cs) * 1024 + (h >> 1) * 32 + (w >> 1)];
  }
  __syncthreads();
  {
    int ci = tid & 63, wq = tid >> 6;
    for (int ws2 = wq; ws2 < 64; ws2 += 4)
      Xn[((((size_t)b * 66 + h + 1) * 66) + 1 + ws2) * 768 + 256 + ci0 + ci] = f2b(tile[ci][ws2]);
  }
}

// ---------------- K4c: weight repack Wc(256,768,3,3) f32 -> Wb(256,9,768) bf16
__global__ __launch_bounds__(256) void k_wb(
    const float* __restrict__ Wc, short* __restrict__ Wb)
{
  int i = blockIdx.x * 256 + threadIdx.x;
  int o = i / 6912;
  int rem = i - o * 6912;
  int khw = rem / 768;
  int ci = rem - khw * 768;
  Wb[i] = f2b(Wc[(size_t)o * 6912 + ci * 9 + khw]);
}

// ---------------- K5: 3x3 conv, 64x64 wave tiles + K-split x2, NO atomics.
// (R11/R12-verified.) ks=0 -> plain f32 into outf (= d_out, each elem once);
// ks=1 -> bf16 partial into cb1. k_inorm fuses the two-partial sum.
// Grid 32x4x4 = 512 = 2 blocks/CU.
__global__ __launch_bounds__(256, 2) void k_conv_mfma(
    const short* __restrict__ Xn,   // (B,66,66,768) bf16, guard ring zero
    const short* __restrict__ Wb,   // (256,9,768) bf16
    float* __restrict__ outf,       // (B,256,4096) f32: ks=0 partial (= d_out)
    short* __restrict__ cb1)        // (B,256,4096) bf16: ks=1 partial
{
  __shared__ __align__(16) short Wl[384 * 64];  // 48 KB [kw*128+cout][64ci]
  __shared__ __align__(16) short Xl[132 * 64];  // 16.5 KB [xrow*66+px][64ci]
  const int tid = threadIdx.x;
  const int wv = tid >> 6;
  const int lane = tid & 63;
  const int t = lane & 15, q = lane >> 4;
  const int wm = wv >> 1, wn = wv & 1;
  const int h0 = blockIdx.x * 2;           // output rows h0, h0+1
  const int m0 = (blockIdx.y >> 1) * 128;  // cout half
  const int ks = blockIdx.y & 1;           // ci half
  const int b = blockIdx.z;

  const f32x4 zf = {0.f, 0.f, 0.f, 0.f};
  f32x4 acc[4][4];
#pragma unroll
  for (int mt = 0; mt < 4; ++mt)
#pragma unroll
    for (int nt = 0; nt < 4; ++nt) acc[mt][nt] = zf;

  for (int kh = 0; kh < 3; ++kh) {
    const short* wsrc = Wb + (size_t)m0 * 6912 + (kh * 3) * 768 + ks * 384;
    const short* xsrc = Xn + ((size_t)b * 66 + h0 + kh) * 66 * 768 + ks * 384;
    for (int c6 = 0; c6 < 6; ++c6) {
      int ci0 = c6 * 64;
      // stage W: 384 rows x 8 granules = 3072; 12 DMA/thread
#pragma unroll
      for (int r = 0; r < 12; ++r) {
        int e = tid + (r << 8);
        int g = e & 7, row = e >> 3;
        int kw = row >> 7, cl = row & 127;
        int gs = g ^ (row & 7);
        gl16(wsrc + (size_t)cl * 6912 + kw * 768 + ci0 + gs * 8, Wl + e * 8);
      }
      // stage X: 2 rows x 66 px x 8 granules = 1056
#pragma unroll
      for (int r = 0; r < 5; ++r) {
        int e = tid + (r << 8);
        if (e < 1056) {
          int g = e & 7, prow = e >> 3;
          int xrow = (prow * 993) >> 16;         // prow / 66, valid 0..131
          int px = prow - xrow * 66;
          int gs = g ^ (prow & 7);
          gl16(xsrc + ((size_t)xrow * 66 + px) * 768 + ci0 + gs * 8, Xl + e * 8);
        }
      }
      __syncthreads();
#pragma unroll
      for (int kw = 0; kw < 3; ++kw) {
        bf16x8 af[4][2], bfr[4][2];
#pragma unroll
        for (int kk = 0; kk < 2; ++kk) {
#pragma unroll
          for (int mt = 0; mt < 4; ++mt) {
            int row = kw * 128 + wm * 64 + mt * 16 + t;
            int g = (kk * 4 + q) ^ (row & 7);
            af[mt][kk] = *(const bf16x8*)(Wl + row * 64 + g * 8);
          }
#pragma unroll
          for (int nt = 0; nt < 4; ++nt) {
            int prow = wn * 66 + nt * 16 + t + kw;
            int g = (kk * 4 + q) ^ (prow & 7);
            bfr[nt][kk] = *(const bf16x8*)(Xl + prow * 64 + g * 8);
          }
        }
#pragma unroll
        for (int kk = 0; kk < 2; ++kk)
#pragma unroll
          for (int mt = 0; mt < 4; ++mt)
#pragma unroll
            for (int nt = 0; nt < 4; ++nt)
              acc[mt][nt] = __builtin_amdgcn_mfma_f32_16x16x32_bf16(
                  af[mt][kk], bfr[nt][kk], acc[mt][nt], 0, 0, 0);
      }
      __syncthreads();
    }
  }
  // epilogue: outch = m0 + wm*64 + mt*16 + q*4 + r ; out row = h0+wn ;
  // px-in-row = nt*16 + t. Plain stores to disjoint per-ks buffers.
  const int orow = h0 + wn;
  if (ks == 0) {
#pragma unroll
    for (int mt = 0; mt < 4; ++mt) {
      int om = m0 + wm * 64 + mt * 16 + q * 4;
#pragma unroll
      for (int r = 0; r < 4; ++r) {
        float* dst = outf + ((size_t)b * CC + om + r) * HW + orow * 64;
#pragma unroll
        for (int nt = 0; nt < 4; ++nt)
          dst[nt * 16 + t] = acc[mt][nt][r];
      }
    }
  } else {
#pragma unroll
    for (int mt = 0; mt < 4; ++mt) {
      int om = m0 + wm * 64 + mt * 16 + q * 4;
#pragma unroll
      for (int r = 0; r < 4; ++r) {
        short* dst = cb1 + ((size_t)b * CC + om + r) * HW + orow * 64;
#pragma unroll
        for (int nt = 0; nt < 4; ++nt)
          dst[nt * 16 + t] = f2b(acc[mt][nt][r]);
      }
    }
  }
}

// ---------------- K6: sum two conv partials (f32 + bf16), then
// InstanceNorm (biased var, eps=1e-5) + ReLU; writes d_out IN PLACE over
// the f32 partial. In/out alias -> no __restrict__; whole channel staged
// in LDS behind a barrier before any write; blocks own disjoint channels.
__global__ __launch_bounds__(256) void k_inorm(
    const float* p0, const short* __restrict__ p1, float* out)
{
  __shared__ float buf[4096];
  __shared__ float red[8];
  const int tid = threadIdx.x;
  const int ch = blockIdx.x;
  const float* s0 = p0 + (size_t)ch * HW;
  const short* s1 = p1 + (size_t)ch * HW;

  float s = 0.f, sq = 0.f;
#pragma unroll
  for (int u = 0; u < 4; ++u) {
    int idx = u * 1024 + tid * 4;
    float4 a = *(const float4*)&s0[idx];
    uint2 pb = *(const uint2*)&s1[idx];
    float v0 = a.x + __uint_as_float(pb.x << 16);
    float v1 = a.y + __uint_as_float(pb.x & 0xffff0000u);
    float v2 = a.z + __uint_as_float(pb.y << 16);
    float v3 = a.w + __uint_as_float(pb.y & 0xffff0000u);
    buf[idx + 0] = v0; buf[idx + 1] = v1;
    buf[idx + 2] = v2; buf[idx + 3] = v3;
    s += v0 + v1 + v2 + v3;
    sq += v0 * v0 + v1 * v1 + v2 * v2 + v3 * v3;
  }
#pragma unroll
  for (int m = 32; m >= 1; m >>= 1) {
    s  += __shfl_xor(s, m, 64);
    sq += __shfl_xor(sq, m, 64);
  }
  if ((tid & 63) == 0) { red[tid >> 6] = s; red[4 + (tid >> 6)] = sq; }
  __syncthreads();
  if (tid == 0) {
    float S = red[0] + red[1] + red[2] + red[3];
    float Q = red[4] + red[5] + red[6] + red[7];
    float mean = S * (1.f / HW);
    float var = Q * (1.f / HW) - mean * mean;
    red[0] = mean;
    red[1] = rsqrtf(var + 1e-5f);
  }
  __syncthreads();
  const float mean = red[0], rs = red[1];
#pragma unroll
  for (int u = 0; u < 4; ++u) {
    int idx = u * 1024 + tid * 4;
    float4 v = *(const float4*)&buf[idx];
    float4 o4 = make_float4(fmaxf((v.x - mean) * rs, 0.f),
                            fmaxf((v.y - mean) * rs, 0.f),
                            fmaxf((v.z - mean) * rs, 0.f),
                            fmaxf((v.w - mean) * rs, 0.f));
    *(float4*)&out[(size_t)ch * HW + idx] = o4;
  }
}

extern "C" void kernel_launch(void* const* d_in, const int* in_sizes, int n_in,
                              void* d_out, int out_size, void* d_ws, size_t ws_size,
                              hipStream_t stream) {
  const float* src  = (const float*)d_in[0];
  const float* tgt  = (const float*)d_in[1];
  const float* prev = (const float*)d_in[2];
  const float* Wq = (const float*)d_in[3];  const float* bq = (const float*)d_in[4];
  const float* Wk = (const float*)d_in[5];  const float* bk = (const float*)d_in[6];
  const float* Wv = (const float*)d_in[7];  const float* bv = (const float*)d_in[8];
  const float* Wp = (const float*)d_in[9];  const float* bp = (const float*)d_in[10];
  const float* gamma = (const float*)d_in[11];
  const float* Wc = (const float*)d_in[12];
  // bcw (d_in[13]) intentionally unused: InstanceNorm(affine=False) is
  // invariant to per-channel constant bias (and bc == 0 in this problem).

  float* ws = (float*)d_ws;
  // float-unit offsets; lifetimes:
  short* qb = (short*)ws;                 // [0, 1048576)        dead after k_attn2
  short* kb = (short*)(ws + 1048576);     // [1048576, 2097152)  dead after k_attn2
  short* vb = (short*)(ws + 2097152);     // [2097152, 3145728)  dead after k_vs
  float* rl = ws + 3145728;               // [3145728, 3162112)  dead after k_vs
  short* vs = (short*)(ws + 3162112);     // [3162112, 4210688)  dead after k_attn2
  short* Xn = (short*)ws;                 // [0, 6690816 floats) (B,66,66,768) bf16
  float* ao = ws + 6690816;               // [6690816, 8787968)  f32 (atomic mode only)
  short* Wb = (short*)(ws + 8787968);     // [8787968, 9672704)  written after k_proj
  float* outf = (float*)d_out;
  short* cb1 = (short*)(ws + 6690816);    // conv ks=1 bf16 partial (after proj)
  // Partial mode (needs ws >= 43,540,480 B): attn partials
  // aop[4][B][HW][DD] bf16 at [6690816, 10885120) — dead after k_proj,
  // so the Wb/cb1 overlaps are safe (both written after k_proj).
  short* aop = (short*)(ws + 6690816);
  const int mode = (ws_size >= 43540480ull) ? 1 : 0;

  k_qkv_mfma<<<dim3(64, 3, BB), 256, 0, stream>>>(src, tgt, Wq, bq, Wk, bk, Wv, bv, qb, kb, vb);
  hipMemsetAsync(rl, 0, (size_t)BB * HW * 4, stream);
  k_lsum2<<<dim3(64, 4, BB), 256, 0, stream>>>(qb, kb, rl);
  k_vs   <<<dim3(2048),      256, 0, stream>>>(vb, rl, vs);
  if (!mode) hipMemsetAsync(ao, 0, (size_t)2097152 * 4, stream);
  k_attn2<<<dim3(32, 4, BB), 256, 0, stream>>>(qb, kb, vs, ao, aop, mode);
  // Xn overlaps qb/kb/vb/rl/vs -> zero only after k_attn2 (also zeroes guard ring)
  hipMemsetAsync(Xn, 0, (size_t)BB * 66 * 66 * 768 * 2, stream);
  k_proj <<<dim3(64, 2, BB), 256, 0, stream>>>(ao, aop, tgt, Wp, bp, gamma, Xn, mode);
  k_pack <<<dim3(64, 8, BB), 256, 0, stream>>>(prev, Xn);
  k_wb   <<<dim3(6912),      256, 0, stream>>>(Wc, Wb);
  k_conv_mfma<<<dim3(32, 4, BB), 256, 0, stream>>>(Xn, Wb, outf, cb1);
  k_inorm<<<dim3(1024),      256, 0, stream>>>(outf, cb1, (float*)d_out);
}